// Round 4
// baseline (2191.531 us; speedup 1.0000x reference)
//
#include <hip/hip_runtime.h>

#define BATCH 32
#define NPTS  8192
#define DIM   64
#define KC    128
#define NITER 10
#define LN_EPS 1e-5f

// ---------------------------------------------------------------------------
// Correctness (round-2/3 lesson): all fp32 implementations of
//   d = (x2 + c2[k]) - 2*dot  IN FP32 make correlated rounding decisions on
// Voronoi-boundary points. Keep distance arithmetic bit-identical to the
// passing round-3 kernel. Center sums: f32 LDS atomics (per-block ~1e-6
// class) + deterministic fp64 cross-block reduce.
//
// d_out doubles as storage: centers region = cen (seeded by ln, rewritten by
// each update; iter-10 leaves finals). soft region temporarily holds the
// per-block partials, overwritten by final_kernel at the end.
// ws: xn fp32 (64MB) | c2 fp32 (16KB)
// ---------------------------------------------------------------------------

#define FMA4(acc, xv, cv) \
    acc = fmaf((xv).w, (cv).w, fmaf((xv).z, (cv).z, fmaf((xv).y, (cv).y, fmaf((xv).x, (cv).x, (acc)))))

// Same accumulation order as round-3 dot64: d0<-x{0,4,8,12}, d1<-x{1,5,9,13}, ...
#define DOT16(res, cbase) do {                                            \
    const float4* _c = (cbase);                                           \
    float _d0 = 0.f, _d1 = 0.f, _d2 = 0.f, _d3 = 0.f;                     \
    FMA4(_d0, x0, _c[0]);   FMA4(_d1, x1, _c[1]);                         \
    FMA4(_d2, x2, _c[2]);   FMA4(_d3, x3, _c[3]);                         \
    FMA4(_d0, x4, _c[4]);   FMA4(_d1, x5, _c[5]);                         \
    FMA4(_d2, x6, _c[6]);   FMA4(_d3, x7, _c[7]);                         \
    FMA4(_d0, x8, _c[8]);   FMA4(_d1, x9, _c[9]);                         \
    FMA4(_d2, x10, _c[10]); FMA4(_d3, x11, _c[11]);                       \
    FMA4(_d0, x12, _c[12]); FMA4(_d1, x13, _c[13]);                       \
    FMA4(_d2, x14, _c[14]); FMA4(_d3, x15, _c[15]);                       \
    res = (_d0 + _d1) + (_d2 + _d3);                                      \
} while (0)

// Same order as round-3 sq64: a0 <- all .x, a1 <- all .y, ...
#define SQ4(xv) do {                       \
    a0 = fmaf((xv).x, (xv).x, a0);         \
    a1 = fmaf((xv).y, (xv).y, a1);         \
    a2 = fmaf((xv).z, (xv).z, a2);         \
    a3 = fmaf((xv).w, (xv).w, a3);         \
} while (0)

#define LOAD_X16(ptr)                                              \
    const float4* xp = (const float4*)(ptr);                       \
    float4 x0 = xp[0], x1 = xp[1], x2 = xp[2], x3 = xp[3];         \
    float4 x4 = xp[4], x5 = xp[5], x6 = xp[6], x7 = xp[7];         \
    float4 x8 = xp[8], x9 = xp[9], x10 = xp[10], x11 = xp[11];     \
    float4 x12 = xp[12], x13 = xp[13], x14 = xp[14], x15 = xp[15]

// One wave per row (unchanged from passing round-3; cen now = d_out region).
__global__ __launch_bounds__(256) void ln_kernel(const float* __restrict__ patches,
                                                 const float* __restrict__ gamma,
                                                 const float* __restrict__ beta,
                                                 float* __restrict__ xn,
                                                 float* __restrict__ cen,
                                                 float* __restrict__ c2) {
    int row = blockIdx.x * 4 + (threadIdx.x >> 6);
    int lane = threadIdx.x & 63;
    size_t base = (size_t)row * DIM + lane;
    float x = patches[base];

    float s = x;
#pragma unroll
    for (int m = 32; m >= 1; m >>= 1) s += __shfl_xor(s, m, 64);
    float mu = s * (1.0f / 64.0f);
    float dx = x - mu;

    float v = dx * dx;
#pragma unroll
    for (int m = 32; m >= 1; m >>= 1) v += __shfl_xor(v, m, 64);
    float var = v * (1.0f / 64.0f);

    float val = dx * (1.0f / sqrtf(var + LN_EPS)) * gamma[lane] + beta[lane];
    xn[base] = val;

    int n = row & (NPTS - 1);
    int b = row >> 13;  // NPTS = 8192 = 2^13
    if (n < KC) {
        cen[((size_t)(b * KC + n)) * DIM + lane] = val;
        float q = val * val;
#pragma unroll
        for (int m = 32; m >= 1; m >>= 1) q += __shfl_xor(q, m, 64);
        if (lane == 0) c2[b * KC + n] = q;
    }
}

// Thread per point. x pinned in 16 named float4 VGPRs; centers scalarized
// (wave-uniform addresses). f32 LDS accumulation, deterministic block flush.
__global__ __launch_bounds__(512, 4) void assign_kernel(const float* __restrict__ xn,
                                                        const float* __restrict__ cen,
                                                        const float* __restrict__ c2,
                                                        float* __restrict__ part,
                                                        float* __restrict__ cntpart) {
    __shared__ float ls[KC * 65];
    __shared__ float lc[KC];
    for (int i = threadIdx.x; i < KC * 65; i += 512) ls[i] = 0.f;
    if (threadIdx.x < KC) lc[threadIdx.x] = 0.f;
    __syncthreads();

    int blk = blockIdx.x;
    int b = blk >> 4;  // 16 blocks per batch
    int p = b * NPTS + ((blk & 15) << 9) + threadIdx.x;

    LOAD_X16(xn + (size_t)p * DIM);
    float a0 = 0.f, a1 = 0.f, a2 = 0.f, a3 = 0.f;
    SQ4(x0); SQ4(x1); SQ4(x2); SQ4(x3); SQ4(x4); SQ4(x5); SQ4(x6); SQ4(x7);
    SQ4(x8); SQ4(x9); SQ4(x10); SQ4(x11); SQ4(x12); SQ4(x13); SQ4(x14); SQ4(x15);
    float xsq = (a0 + a1) + (a2 + a3);

    const float4* cp = (const float4*)(cen + (size_t)b * KC * DIM);
    const float* c2p = c2 + b * KC;

    float best = 3.4e38f;
    int bi = 0;
    for (int k = 0; k < KC; ++k) {
        float dot;
        DOT16(dot, cp + k * 16);
        float t = xsq + c2p[k];       // fp32, reference op order
        float d = t - 2.0f * dot;
        if (d < best) { best = d; bi = k; }  // strict < == argmin first-index
    }

    float* dst = ls + bi * 65;
#define ATM4(j, xv)                            \
    atomicAdd(dst + 4 * (j) + 0, (xv).x);      \
    atomicAdd(dst + 4 * (j) + 1, (xv).y);      \
    atomicAdd(dst + 4 * (j) + 2, (xv).z);      \
    atomicAdd(dst + 4 * (j) + 3, (xv).w)
    ATM4(0, x0); ATM4(1, x1); ATM4(2, x2); ATM4(3, x3);
    ATM4(4, x4); ATM4(5, x5); ATM4(6, x6); ATM4(7, x7);
    ATM4(8, x8); ATM4(9, x9); ATM4(10, x10); ATM4(11, x11);
    ATM4(12, x12); ATM4(13, x13); ATM4(14, x14); ATM4(15, x15);
#undef ATM4
    atomicAdd(&lc[bi], 1.0f);
    __syncthreads();

    float* gp = part + (size_t)blk * KC * DIM;
    for (int i = threadIdx.x; i < KC * DIM; i += 512) {
        int k = i >> 6, d = i & 63;
        gp[i] = ls[k * 65 + d];
    }
    if (threadIdx.x < KC) cntpart[blk * KC + threadIdx.x] = lc[threadIdx.x];
}

// One wave per (b,k): fp64 reduce of 16 f32 block partials -> fp32 center+norm.
__global__ __launch_bounds__(256) void update_kernel(const float* __restrict__ part,
                                                     const float* __restrict__ cntpart,
                                                     float* __restrict__ cen,
                                                     float* __restrict__ c2) {
    int row = blockIdx.x * 4 + (threadIdx.x >> 6);  // b*KC + k
    int lane = threadIdx.x & 63;
    int b = row >> 7;
    int k = row & (KC - 1);

    double s = 0.0;
    float cnt = 0.f;
#pragma unroll
    for (int sub = 0; sub < 16; ++sub) {
        s += (double)part[((size_t)(b * 16 + sub)) * KC * DIM + (size_t)k * DIM + lane];
        cnt += cntpart[(b * 16 + sub) * KC + k];
    }

    size_t idx = (size_t)row * DIM + lane;
    float old = cen[idx];
    float nc = (cnt > 0.f) ? ((float)s / cnt) : old;
    cen[idx] = nc;

    float q = nc * nc;
#pragma unroll
    for (int m = 32; m >= 1; m >>= 1) q += __shfl_xor(q, m, 64);
    if (lane == 0) c2[row] = q;
}

// Thread per point: pass 1 online max+denominator; pass 2 recompute + float4
// stores (64B-line coalesced via register buffering). Same fp32 formula/order.
__global__ __launch_bounds__(512, 4) void final_kernel(const float* __restrict__ xn,
                                                       const float* __restrict__ cen,
                                                       const float* __restrict__ c2,
                                                       float* __restrict__ soft) {
    int b = blockIdx.x >> 4;
    int p = b * NPTS + ((blockIdx.x & 15) << 9) + threadIdx.x;

    LOAD_X16(xn + (size_t)p * DIM);
    float a0 = 0.f, a1 = 0.f, a2 = 0.f, a3 = 0.f;
    SQ4(x0); SQ4(x1); SQ4(x2); SQ4(x3); SQ4(x4); SQ4(x5); SQ4(x6); SQ4(x7);
    SQ4(x8); SQ4(x9); SQ4(x10); SQ4(x11); SQ4(x12); SQ4(x13); SQ4(x14); SQ4(x15);
    float xsq = (a0 + a1) + (a2 + a3);

    const float4* cp = (const float4*)(cen + (size_t)b * KC * DIM);
    const float* c2p = c2 + b * KC;

    float m = -3.4e38f;
    float ssum = 0.f;
    for (int k = 0; k < KC; ++k) {
        float dot;
        DOT16(dot, cp + k * 16);
        float t = xsq + c2p[k];
        float z = -(t - 2.0f * dot);
        if (z > m) {
            ssum = ssum * __expf(m - z) + 1.0f;
            m = z;
        } else {
            ssum += __expf(z - m);
        }
    }
    float rinv = 1.0f / ssum;

    float4* op = (float4*)(soft + (size_t)p * KC);
    for (int kb = 0; kb < KC / 4; ++kb) {
        float e[4];
#pragma unroll
        for (int u = 0; u < 4; ++u) {
            int k = kb * 4 + u;
            float dot;
            DOT16(dot, cp + k * 16);
            float t = xsq + c2p[k];
            float z = -(t - 2.0f * dot);
            e[u] = __expf(z - m) * rinv;
        }
        op[kb] = make_float4(e[0], e[1], e[2], e[3]);
    }
}

extern "C" void kernel_launch(void* const* d_in, const int* in_sizes, int n_in,
                              void* d_out, int out_size, void* d_ws, size_t ws_size,
                              hipStream_t stream) {
    (void)in_sizes; (void)n_in; (void)out_size; (void)ws_size;
    const float* patches = (const float*)d_in[0];
    const float* gamma = (const float*)d_in[1];
    const float* beta = (const float*)d_in[2];
    float* out = (float*)d_out;

    float* ws = (float*)d_ws;
    float* xn = ws;                                   // 16,777,216 f32
    float* c2 = xn + (size_t)BATCH * NPTS * DIM;      // 4,096 f32

    float* cen = out;                                 // centers live in d_out
    float* soft = out + (size_t)BATCH * KC * DIM;
    float* part = soft;                               // 512*8192 f32 (temp)
    float* cntpart = part + (size_t)512 * KC * DIM;   // 512*128 f32 (temp)

    ln_kernel<<<BATCH * NPTS / 4, 256, 0, stream>>>(patches, gamma, beta, xn, cen, c2);

    for (int it = 0; it < NITER; ++it) {
        assign_kernel<<<BATCH * 16, 512, 0, stream>>>(xn, cen, c2, part, cntpart);
        update_kernel<<<BATCH * KC / 4, 256, 0, stream>>>(part, cntpart, cen, c2);
    }

    final_kernel<<<BATCH * 16, 512, 0, stream>>>(xn, cen, c2, soft);
}